// Round 9
// baseline (187.848 us; speedup 1.0000x reference)
//
#include <hip/hip_runtime.h>

constexpr int DIM  = 33;
constexpr int DIM2 = DIM * DIM;        // 1089
constexpr int DIM3 = DIM * DIM * DIM;  // 35937
constexpr int HW    = 1024 * 1024;
constexpr int BATCH = 8;
constexpr int GROUPS_PER_IMG = HW / 4;     // 262144 float4-groups per channel plane
constexpr unsigned LDS_BYTES = DIM3 * 4;   // 143748 B (fits 160 KiB/CU)

static_assert(256 * 1024 == GROUPS_PER_IMG, "grid must cover one image exactly");

// Volatile-asm ordering token: ds_read/global ops cannot cross it, and
// volatile asms keep their mutual program order. Pure ALU may cross (ok).
#define ORDER() asm volatile("")

// Pin a Corn2's 16 corner dwords: this volatile asm is the FIRST consumer of
// the ds_read results, so the waitcnt pass places its precise counted
// s_waitcnt lgkmcnt(N) HERE (N=8 while the other buffer's 8 DS ops are still
// outstanding — lgkm returns are in-order). The FMA tree then depends on the
// asm OUTPUTS, so it cannot be hoisted above the wait: the 2-deep gather
// pipeline survives to the ISA via data dependencies, not fences (which the
// SelectionDAG scheduler ignored for chain-less pure ALU in R6/R7).
#define PIN8(Cb) asm volatile("" \
  : "+v"((Cb).c[0][0]), "+v"((Cb).c[0][1]), "+v"((Cb).c[0][2]), "+v"((Cb).c[0][3]), \
    "+v"((Cb).c[0][4]), "+v"((Cb).c[0][5]), "+v"((Cb).c[0][6]), "+v"((Cb).c[0][7]), \
    "+v"((Cb).c[1][0]), "+v"((Cb).c[1][1]), "+v"((Cb).c[1][2]), "+v"((Cb).c[1][3]), \
    "+v"((Cb).c[1][4]), "+v"((Cb).c[1][5]), "+v"((Cb).c[1][6]), "+v"((Cb).c[1][7]))

// ---------------------------------------------------------------------------
// Tiny prep kernel: quantize+pack the LUT once into workspace.
// One dword per texel: ch0 bits[9:0], ch1 bits[19:10], ch2 bits[29:20].
// ---------------------------------------------------------------------------
__global__ __launch_bounds__(256) void lut_pack_kernel(
    const float* __restrict__ lut, unsigned int* __restrict__ packed)
{
    int i = blockIdx.x * blockDim.x + threadIdx.x;
    if (i < DIM3) {
        float v0 = lut[i];
        float v1 = lut[DIM3 + i];
        float v2 = lut[2 * DIM3 + i];
        unsigned q0 = (unsigned)(fminf(fmaxf(v0, 0.0f), 1.0f) * 1023.0f + 0.5f);
        unsigned q1 = (unsigned)(fminf(fmaxf(v1, 0.0f), 1.0f) * 1023.0f + 0.5f);
        unsigned q2 = (unsigned)(fminf(fmaxf(v2, 0.0f), 1.0f) * 1023.0f + 0.5f);
        packed[i] = q0 | (q1 << 10) | (q2 << 20);
    }
}

// 2-pixel pipeline buffers (constant indices -> SROA to registers)
struct Frac2 { float rd[2], gd[2], bd[2]; };
struct Corn2 { unsigned c[2][8]; };

// ---------------------------------------------------------------------------
// P-stage: index math + issue the 8 LDS gathers for 2 pixels.
// Numerics identical to the verified kernel ((int)t == floorf for t>=0).
// ---------------------------------------------------------------------------
__device__ __forceinline__ void p2(const unsigned int* __restrict__ sLut,
                                   float r0, float g0, float b0,
                                   float r1, float g1, float b1,
                                   Frac2& f, Corn2& C)
{
    const float invbin = 32.0f / 1.000001f;   // 1/binsize
    float R[2] = {r0, r1}, G[2] = {g0, g1}, B[2] = {b0, b1};
#pragma unroll
    for (int i = 0; i < 2; ++i) {
        float tr = R[i] * invbin;
        float tg = G[i] * invbin;
        float tb = B[i] * invbin;
        int ri = (int)tr;
        int gi = (int)tg;
        int bi = (int)tb;
        ri = ri < 0 ? 0 : (ri > DIM - 2 ? DIM - 2 : ri);
        gi = gi < 0 ? 0 : (gi > DIM - 2 ? DIM - 2 : gi);
        bi = bi < 0 ? 0 : (bi > DIM - 2 ? DIM - 2 : bi);
        f.rd[i] = tr - (float)ri;
        f.gd[i] = tg - (float)gi;
        f.bd[i] = tb - (float)bi;
        int base = bi * DIM2 + gi * DIM + ri;
        // adjacent r-pairs -> ds_read2_b32
        C.c[i][0] = sLut[base];
        C.c[i][1] = sLut[base + 1];
        C.c[i][2] = sLut[base + DIM];
        C.c[i][3] = sLut[base + DIM + 1];
        C.c[i][4] = sLut[base + DIM2];
        C.c[i][5] = sLut[base + DIM2 + 1];
        C.c[i][6] = sLut[base + DIM2 + DIM];
        C.c[i][7] = sLut[base + DIM2 + DIM + 1];
    }
}

// ---------------------------------------------------------------------------
// C-stage: weights + unpack + FMA tree for 2 pixels.
// BYTE-IDENTICAL accumulate order to the verified 65us kernel.
// ---------------------------------------------------------------------------
__device__ __forceinline__ void c2(const Frac2& f, const Corn2& C,
                                   float o0[2], float o1[2], float o2[2])
{
    const float dq = 1.0f / 1023.0f;
#pragma unroll
    for (int i = 0; i < 2; ++i) {
        float rd = f.rd[i], gd = f.gd[i], bd = f.bd[i];
        unsigned c000 = C.c[i][0], c001 = C.c[i][1];
        unsigned c010 = C.c[i][2], c011 = C.c[i][3];
        unsigned c100 = C.c[i][4], c101 = C.c[i][5];
        unsigned c110 = C.c[i][6], c111 = C.c[i][7];

        float wr1 = rd, wr0 = 1.0f - rd;
        float wg1 = gd, wg0 = 1.0f - gd;
        float wb1 = bd, wb0 = 1.0f - bd;

        float w000 = wb0 * wg0 * wr0;
        float w001 = wb0 * wg0 * wr1;
        float w010 = wb0 * wg1 * wr0;
        float w011 = wb0 * wg1 * wr1;
        float w100 = wb1 * wg0 * wr0;
        float w101 = wb1 * wg0 * wr1;
        float w110 = wb1 * wg1 * wr0;
        float w111 = wb1 * wg1 * wr1;

        float a0 = w000 * (float)(c000 & 1023u) + w001 * (float)(c001 & 1023u)
                 + w010 * (float)(c010 & 1023u) + w011 * (float)(c011 & 1023u)
                 + w100 * (float)(c100 & 1023u) + w101 * (float)(c101 & 1023u)
                 + w110 * (float)(c110 & 1023u) + w111 * (float)(c111 & 1023u);

        float a1 = w000 * (float)((c000 >> 10) & 1023u) + w001 * (float)((c001 >> 10) & 1023u)
                 + w010 * (float)((c010 >> 10) & 1023u) + w011 * (float)((c011 >> 10) & 1023u)
                 + w100 * (float)((c100 >> 10) & 1023u) + w101 * (float)((c101 >> 10) & 1023u)
                 + w110 * (float)((c110 >> 10) & 1023u) + w111 * (float)((c111 >> 10) & 1023u);

        float a2 = w000 * (float)(c000 >> 20) + w001 * (float)(c001 >> 20)
                 + w010 * (float)(c010 >> 20) + w011 * (float)(c011 >> 20)
                 + w100 * (float)(c100 >> 20) + w101 * (float)(c101 >> 20)
                 + w110 * (float)(c110 >> 20) + w111 * (float)(c111 >> 20);

        o0[i] = a0 * dq;
        o1[i] = a1 * dq;
        o2[i] = a2 * dq;
    }
}

// ---------------------------------------------------------------------------
// Main kernel: 2-deep LDS-gather pipeline enforced by data dependencies.
// Per image: issue E gathers (px0,px1) | ORDER | issue O gathers (px2,px3)
// + global prefetch | PIN8(E) -> precise lgkmcnt(8) wait | consume E |
// PIN8(O) -> lgkmcnt(0) | consume O | store. 16 DS ops in flight while the
// first 8 are consumed — the first variant whose pipeline provably reaches
// the ISA (signature: VGPR ~80-100 from 32 live corner dwords).
// ---------------------------------------------------------------------------
template <bool PREPACKED>
__global__ __launch_bounds__(1024) void lut3d_apply_kernel(
    const unsigned int* __restrict__ plut,   // packed LUT in workspace (PREPACKED)
    const float* __restrict__ lut,           // raw LUT (fallback path)
    const float* __restrict__ x,             // (8, 3, 1024, 1024)
    float* __restrict__ out)                 // (8, 3, 1024, 1024)
{
    extern __shared__ unsigned int sLut[];   // DIM3 dwords

    if constexpr (PREPACKED) {
        const uint4* p4 = reinterpret_cast<const uint4*>(plut);
        uint4* s4 = reinterpret_cast<uint4*>(sLut);
        for (int i = threadIdx.x; i < DIM3 / 4; i += 1024) s4[i] = p4[i];
        if (threadIdx.x == 0) sLut[DIM3 - 1] = plut[DIM3 - 1];
    } else {
        for (int i = threadIdx.x; i < DIM3; i += 1024) {
            float v0 = lut[i];
            float v1 = lut[DIM3 + i];
            float v2 = lut[2 * DIM3 + i];
            unsigned q0 = (unsigned)(fminf(fmaxf(v0, 0.0f), 1.0f) * 1023.0f + 0.5f);
            unsigned q1 = (unsigned)(fminf(fmaxf(v1, 0.0f), 1.0f) * 1023.0f + 0.5f);
            unsigned q2 = (unsigned)(fminf(fmaxf(v2, 0.0f), 1.0f) * 1023.0f + 0.5f);
            sLut[i] = q0 | (q1 << 10) | (q2 << 20);
        }
    }
    __syncthreads();

    const int q = blockIdx.x * blockDim.x + threadIdx.x;   // [0, GROUPS_PER_IMG)
    const float4* __restrict__ xp = reinterpret_cast<const float4*>(x);
    float4* __restrict__ op = reinterpret_cast<float4*>(out);

    auto iplane = [&](int img, int ch) -> size_t {
        return ((size_t)img * 3 + ch) * GROUPS_PER_IMG + q;
    };

    float4 rv = xp[iplane(0, 0)], gv = xp[iplane(0, 1)], bv = xp[iplane(0, 2)];

#pragma unroll 1
    for (int b = 0; b < BATCH; ++b) {
        Frac2 fE, fO;
        Corn2 cE, cO;
        float oE0[2], oE1[2], oE2[2], oO0[2], oO1[2], oO2[2];

        // P(E): px0,px1 — 8 DS ops issued
        p2(sLut, rv.x, gv.x, bv.x, rv.y, gv.y, bv.y, fE, cE);
        ORDER();   // P(O)'s reads may not move above this point
        // P(O): px2,px3 — 8 more DS ops issued (16 outstanding)
        p2(sLut, rv.z, gv.z, bv.z, rv.w, gv.w, bv.w, fO, cO);

        // global prefetch of next image rides under the LDS pipeline
        int nx = b + 1 < BATCH ? b + 1 : b;
        float4 rn = xp[iplane(nx, 0)];
        float4 gn = xp[iplane(nx, 1)];
        float4 bn = xp[iplane(nx, 2)];

        PIN8(cE);                       // precise s_waitcnt lgkmcnt(8) here
        c2(fE, cE, oE0, oE1, oE2);      // consume E while O's 8 in flight

        PIN8(cO);                       // s_waitcnt lgkmcnt(0)
        c2(fO, cO, oO0, oO1, oO2);

        op[iplane(b, 0)] = make_float4(oE0[0], oE0[1], oO0[0], oO0[1]);
        op[iplane(b, 1)] = make_float4(oE1[0], oE1[1], oO1[0], oO1[1]);
        op[iplane(b, 2)] = make_float4(oE2[0], oE2[1], oO2[0], oO2[1]);

        rv = rn; gv = gn; bv = bn;
    }
}

extern "C" void kernel_launch(void* const* d_in, const int* in_sizes, int n_in,
                              void* d_out, int out_size, void* d_ws, size_t ws_size,
                              hipStream_t stream) {
    const float* lut = (const float*)d_in[0];  // 3*33*33*33
    const float* x   = (const float*)d_in[1];  // 8*3*1024*1024
    float* out = (float*)d_out;

    // 140 KB LDS -> 1 block/CU; 1024 threads = 16 waves/CU; 256 blocks = 1/CU.
    if (ws_size >= (size_t)LDS_BYTES && d_ws != nullptr) {
        unsigned int* packed = (unsigned int*)d_ws;
        lut_pack_kernel<<<(DIM3 + 255) / 256, 256, 0, stream>>>(lut, packed);
        lut3d_apply_kernel<true><<<256, 1024, LDS_BYTES, stream>>>(packed, lut, x, out);
    } else {
        lut3d_apply_kernel<false><<<256, 1024, LDS_BYTES, stream>>>(nullptr, lut, x, out);
    }
}

// Round 10
// 187.408 us; speedup vs baseline: 1.0023x; 1.0023x over previous
//
#include <hip/hip_runtime.h>

constexpr int DIM  = 33;
constexpr int DIM2 = DIM * DIM;        // 1089
constexpr int DIM3 = DIM * DIM * DIM;  // 35937
constexpr int HW    = 1024 * 1024;
constexpr int BATCH = 8;
constexpr int GROUPS_PER_IMG = HW / 4;     // 262144 float4-groups per channel plane
constexpr unsigned LDS_BYTES = DIM3 * 4;   // 143748 B (fits 160 KiB/CU)

static_assert(256 * 1024 == GROUPS_PER_IMG, "grid must cover one image exactly");

// Per-pixel pipeline buffers (constant indices -> SROA to registers)
struct Corn { unsigned c[8]; };
struct Frac { float rd, gd, bd; };

// The conjunction that neither R6 nor R9 had:
//  - "+v" data deps: the consumer FMA tree reads the ASM'S outputs, so it
//    cannot be hoisted above this point (defeats the ALU hoisting of R6/R7);
//  - "memory" clobber: NO load/store may cross in either direction, so the
//    other pixels' ds_reads issued before this point cannot SINK below it
//    (defeats the load sinking of R9).
// AMDGPUInsertWaitcnts is per-register precise -> emits counted
// s_waitcnt lgkmcnt(12/8/4/0) at the four PINs: a 4-deep gather pipeline
// that provably reaches the ISA (signature: VGPR ~90-110).
#define PINM(Cb) asm volatile("" \
  : "+v"((Cb).c[0]), "+v"((Cb).c[1]), "+v"((Cb).c[2]), "+v"((Cb).c[3]), \
    "+v"((Cb).c[4]), "+v"((Cb).c[5]), "+v"((Cb).c[6]), "+v"((Cb).c[7]) \
  :: "memory")

// ---------------------------------------------------------------------------
// Tiny prep kernel: quantize+pack the LUT once into workspace.
// One dword per texel: ch0 bits[9:0], ch1 bits[19:10], ch2 bits[29:20].
// ---------------------------------------------------------------------------
__global__ __launch_bounds__(256) void lut_pack_kernel(
    const float* __restrict__ lut, unsigned int* __restrict__ packed)
{
    int i = blockIdx.x * blockDim.x + threadIdx.x;
    if (i < DIM3) {
        float v0 = lut[i];
        float v1 = lut[DIM3 + i];
        float v2 = lut[2 * DIM3 + i];
        unsigned q0 = (unsigned)(fminf(fmaxf(v0, 0.0f), 1.0f) * 1023.0f + 0.5f);
        unsigned q1 = (unsigned)(fminf(fmaxf(v1, 0.0f), 1.0f) * 1023.0f + 0.5f);
        unsigned q2 = (unsigned)(fminf(fmaxf(v2, 0.0f), 1.0f) * 1023.0f + 0.5f);
        packed[i] = q0 | (q1 << 10) | (q2 << 20);
    }
}

// ---------------------------------------------------------------------------
// P-stage (one pixel): index math + issue the 8 LDS gathers (4x ds_read2_b32).
// Numerics identical to the verified kernel ((int)t == floorf for t>=0).
// ---------------------------------------------------------------------------
__device__ __forceinline__ void p1(const unsigned int* __restrict__ sLut,
                                   float r, float g, float b, Frac& f, Corn& C)
{
    const float invbin = 32.0f / 1.000001f;   // 1/binsize
    float tr = r * invbin;
    float tg = g * invbin;
    float tb = b * invbin;
    int ri = (int)tr;
    int gi = (int)tg;
    int bi = (int)tb;
    ri = ri < 0 ? 0 : (ri > DIM - 2 ? DIM - 2 : ri);
    gi = gi < 0 ? 0 : (gi > DIM - 2 ? DIM - 2 : gi);
    bi = bi < 0 ? 0 : (bi > DIM - 2 ? DIM - 2 : bi);
    f.rd = tr - (float)ri;
    f.gd = tg - (float)gi;
    f.bd = tb - (float)bi;
    int base = bi * DIM2 + gi * DIM + ri;
    C.c[0] = sLut[base];
    C.c[1] = sLut[base + 1];
    C.c[2] = sLut[base + DIM];
    C.c[3] = sLut[base + DIM + 1];
    C.c[4] = sLut[base + DIM2];
    C.c[5] = sLut[base + DIM2 + 1];
    C.c[6] = sLut[base + DIM2 + DIM];
    C.c[7] = sLut[base + DIM2 + DIM + 1];
}

// ---------------------------------------------------------------------------
// C-stage (one pixel): weights + unpack + FMA tree.
// BYTE-IDENTICAL accumulate order to the verified 65us kernel.
// ---------------------------------------------------------------------------
__device__ __forceinline__ void c1(const Frac& f, const Corn& C,
                                   float& o0, float& o1, float& o2)
{
    const float dq = 1.0f / 1023.0f;
    float rd = f.rd, gd = f.gd, bd = f.bd;
    unsigned c000 = C.c[0], c001 = C.c[1], c010 = C.c[2], c011 = C.c[3];
    unsigned c100 = C.c[4], c101 = C.c[5], c110 = C.c[6], c111 = C.c[7];

    float wr1 = rd, wr0 = 1.0f - rd;
    float wg1 = gd, wg0 = 1.0f - gd;
    float wb1 = bd, wb0 = 1.0f - bd;

    float w000 = wb0 * wg0 * wr0;
    float w001 = wb0 * wg0 * wr1;
    float w010 = wb0 * wg1 * wr0;
    float w011 = wb0 * wg1 * wr1;
    float w100 = wb1 * wg0 * wr0;
    float w101 = wb1 * wg0 * wr1;
    float w110 = wb1 * wg1 * wr0;
    float w111 = wb1 * wg1 * wr1;

    float a0 = w000 * (float)(c000 & 1023u) + w001 * (float)(c001 & 1023u)
             + w010 * (float)(c010 & 1023u) + w011 * (float)(c011 & 1023u)
             + w100 * (float)(c100 & 1023u) + w101 * (float)(c101 & 1023u)
             + w110 * (float)(c110 & 1023u) + w111 * (float)(c111 & 1023u);

    float a1 = w000 * (float)((c000 >> 10) & 1023u) + w001 * (float)((c001 >> 10) & 1023u)
             + w010 * (float)((c010 >> 10) & 1023u) + w011 * (float)((c011 >> 10) & 1023u)
             + w100 * (float)((c100 >> 10) & 1023u) + w101 * (float)((c101 >> 10) & 1023u)
             + w110 * (float)((c110 >> 10) & 1023u) + w111 * (float)((c111 >> 10) & 1023u);

    float a2 = w000 * (float)(c000 >> 20) + w001 * (float)(c001 >> 20)
             + w010 * (float)(c010 >> 20) + w011 * (float)(c011 >> 20)
             + w100 * (float)(c100 >> 20) + w101 * (float)(c101 >> 20)
             + w110 * (float)(c110 >> 20) + w111 * (float)(c111 >> 20);

    o0 = a0 * dq;
    o1 = a1 * dq;
    o2 = a2 * dq;
}

// ---------------------------------------------------------------------------
// Main kernel: 4-deep LDS-gather pipeline enforced by data deps + "memory"
// clobber. Per image: issue ALL 16 ds_read2 (px0..px3), global prefetch of
// the next image, then consume px0 at lgkmcnt(12), px1 at (8), px2 at (4),
// px3 at (0). 16 DS ops in flight while the first 4 are consumed.
// ---------------------------------------------------------------------------
template <bool PREPACKED>
__global__ __launch_bounds__(1024) void lut3d_apply_kernel(
    const unsigned int* __restrict__ plut,   // packed LUT in workspace (PREPACKED)
    const float* __restrict__ lut,           // raw LUT (fallback path)
    const float* __restrict__ x,             // (8, 3, 1024, 1024)
    float* __restrict__ out)                 // (8, 3, 1024, 1024)
{
    extern __shared__ unsigned int sLut[];   // DIM3 dwords

    if constexpr (PREPACKED) {
        const uint4* p4 = reinterpret_cast<const uint4*>(plut);
        uint4* s4 = reinterpret_cast<uint4*>(sLut);
        for (int i = threadIdx.x; i < DIM3 / 4; i += 1024) s4[i] = p4[i];
        if (threadIdx.x == 0) sLut[DIM3 - 1] = plut[DIM3 - 1];
    } else {
        for (int i = threadIdx.x; i < DIM3; i += 1024) {
            float v0 = lut[i];
            float v1 = lut[DIM3 + i];
            float v2 = lut[2 * DIM3 + i];
            unsigned q0 = (unsigned)(fminf(fmaxf(v0, 0.0f), 1.0f) * 1023.0f + 0.5f);
            unsigned q1 = (unsigned)(fminf(fmaxf(v1, 0.0f), 1.0f) * 1023.0f + 0.5f);
            unsigned q2 = (unsigned)(fminf(fmaxf(v2, 0.0f), 1.0f) * 1023.0f + 0.5f);
            sLut[i] = q0 | (q1 << 10) | (q2 << 20);
        }
    }
    __syncthreads();

    const int q = blockIdx.x * blockDim.x + threadIdx.x;   // [0, GROUPS_PER_IMG)
    const float4* __restrict__ xp = reinterpret_cast<const float4*>(x);
    float4* __restrict__ op = reinterpret_cast<float4*>(out);

    auto iplane = [&](int img, int ch) -> size_t {
        return ((size_t)img * 3 + ch) * GROUPS_PER_IMG + q;
    };

    float4 rv = xp[iplane(0, 0)], gv = xp[iplane(0, 1)], bv = xp[iplane(0, 2)];

#pragma unroll 1
    for (int b = 0; b < BATCH; ++b) {
        Frac f0, f1, f2, f3;
        Corn C0, C1, C2, C3;

        // ---- P: issue all 16 ds_read2 for the 4 pixels ----
        p1(sLut, rv.x, gv.x, bv.x, f0, C0);
        p1(sLut, rv.y, gv.y, bv.y, f1, C1);
        p1(sLut, rv.z, gv.z, bv.z, f2, C2);
        p1(sLut, rv.w, gv.w, bv.w, f3, C3);

        // global prefetch of next image rides under the LDS pipeline
        int nx = b + 1 < BATCH ? b + 1 : b;
        float4 rn = xp[iplane(nx, 0)];
        float4 gn = xp[iplane(nx, 1)];
        float4 bn = xp[iplane(nx, 2)];

        // ---- C: consume in issue order with counted lgkmcnt waits ----
        float o00, o01, o02, o10, o11, o12, o20, o21, o22, o30, o31, o32;
        PINM(C0);                       // s_waitcnt lgkmcnt(12)
        c1(f0, C0, o00, o01, o02);
        PINM(C1);                       // s_waitcnt lgkmcnt(8)
        c1(f1, C1, o10, o11, o12);
        PINM(C2);                       // s_waitcnt lgkmcnt(4)
        c1(f2, C2, o20, o21, o22);
        PINM(C3);                       // s_waitcnt lgkmcnt(0)
        c1(f3, C3, o30, o31, o32);

        op[iplane(b, 0)] = make_float4(o00, o10, o20, o30);
        op[iplane(b, 1)] = make_float4(o01, o11, o21, o31);
        op[iplane(b, 2)] = make_float4(o02, o12, o22, o32);

        rv = rn; gv = gn; bv = bn;
    }
}

extern "C" void kernel_launch(void* const* d_in, const int* in_sizes, int n_in,
                              void* d_out, int out_size, void* d_ws, size_t ws_size,
                              hipStream_t stream) {
    const float* lut = (const float*)d_in[0];  // 3*33*33*33
    const float* x   = (const float*)d_in[1];  // 8*3*1024*1024
    float* out = (float*)d_out;

    // 140 KB LDS -> 1 block/CU; 1024 threads = 16 waves/CU; 256 blocks = 1/CU.
    if (ws_size >= (size_t)LDS_BYTES && d_ws != nullptr) {
        unsigned int* packed = (unsigned int*)d_ws;
        lut_pack_kernel<<<(DIM3 + 255) / 256, 256, 0, stream>>>(lut, packed);
        lut3d_apply_kernel<true><<<256, 1024, LDS_BYTES, stream>>>(packed, lut, x, out);
    } else {
        lut3d_apply_kernel<false><<<256, 1024, LDS_BYTES, stream>>>(nullptr, lut, x, out);
    }
}

// Round 11
// 187.185 us; speedup vs baseline: 1.0035x; 1.0012x over previous
//
#include <hip/hip_runtime.h>

constexpr int DIM  = 33;
constexpr int DIM2 = DIM * DIM;        // 1089
constexpr int DIM3 = DIM * DIM * DIM;  // 35937
constexpr int HW    = 1024 * 1024;
constexpr int BATCH = 8;
constexpr int GROUPS_PER_IMG = HW / 4;     // 262144 float4-groups per channel plane
constexpr unsigned LDS_BYTES = DIM3 * 4;   // 143748 B (fits 160 KiB/CU)

static_assert(256 * 1024 == GROUPS_PER_IMG, "grid must cover one image exactly");

typedef unsigned int v2u __attribute__((ext_vector_type(2)));  // VGPR pair

// ---------------------------------------------------------------------------
// Tiny prep kernel: quantize+pack the LUT once into workspace.
// One dword per texel: ch0 bits[9:0], ch1 bits[19:10], ch2 bits[29:20].
// ---------------------------------------------------------------------------
__global__ __launch_bounds__(256) void lut_pack_kernel(
    const float* __restrict__ lut, unsigned int* __restrict__ packed)
{
    int i = blockIdx.x * blockDim.x + threadIdx.x;
    if (i < DIM3) {
        float v0 = lut[i];
        float v1 = lut[DIM3 + i];
        float v2 = lut[2 * DIM3 + i];
        unsigned q0 = (unsigned)(fminf(fmaxf(v0, 0.0f), 1.0f) * 1023.0f + 0.5f);
        unsigned q1 = (unsigned)(fminf(fmaxf(v1, 0.0f), 1.0f) * 1023.0f + 0.5f);
        unsigned q2 = (unsigned)(fminf(fmaxf(v2, 0.0f), 1.0f) * 1023.0f + 0.5f);
        packed[i] = q0 | (q1 << 10) | (q2 << 20);
    }
}

// ---------------------------------------------------------------------------
// Issue one pixel's 8 corner gathers as literal ISA (4x ds_read2_b32).
// Volatile asm: ISel/MachineScheduler cannot reorder these against other
// volatile asms or delete them — the pipeline is guaranteed to reach HW.
// Pair layout: A=(c000,c001) B=(c010,c011) C=(c100,c101) D=(c110,c111).
// offset0/offset1 are DWORD-scaled for the b32 variant (33,34 < 256 ok).
// ---------------------------------------------------------------------------
__device__ __forceinline__ void gather_px(unsigned lutByteBase, int base,
                                          v2u& A, v2u& B, v2u& C, v2u& D)
{
    unsigned a0 = lutByteBase + (unsigned)base * 4u;
    unsigned a1 = a0 + (unsigned)(DIM2 * 4);   // + b-slice (1089 dwords)
    asm volatile(
        "ds_read2_b32 %0, %4 offset0:0 offset1:1\n\t"
        "ds_read2_b32 %1, %4 offset0:33 offset1:34\n\t"
        "ds_read2_b32 %2, %5 offset0:0 offset1:1\n\t"
        "ds_read2_b32 %3, %5 offset0:33 offset1:34"
        : "=&v"(A), "=&v"(B), "=&v"(C), "=&v"(D)
        : "v"(a0), "v"(a1));
}

// Hand-counted wait: lgkmcnt(N) lets the OTHER pixels' DS ops stay in flight.
// The pixel's 4 pairs ride through as "+v" data deps, so the consuming FMA
// tree cannot be hoisted above the wait — and there is NO "memory" clobber,
// so the waitcnt pass does not insert a conservative full drain (R10's bug).
#define WAITPIN(N, A, B, C, D) \
    asm volatile("s_waitcnt lgkmcnt(" #N ")" : "+v"(A), "+v"(B), "+v"(C), "+v"(D))

// ---------------------------------------------------------------------------
// Index math for one pixel (identical numerics to all verified versions).
// ---------------------------------------------------------------------------
__device__ __forceinline__ void idx_px(float r, float g, float b,
                                       float& rd, float& gd, float& bd, int& base)
{
    const float invbin = 32.0f / 1.000001f;   // 1/binsize
    float tr = r * invbin;
    float tg = g * invbin;
    float tb = b * invbin;
    int ri = (int)tr;
    int gi = (int)tg;
    int bi = (int)tb;
    ri = ri < 0 ? 0 : (ri > DIM - 2 ? DIM - 2 : ri);
    gi = gi < 0 ? 0 : (gi > DIM - 2 ? DIM - 2 : gi);
    bi = bi < 0 ? 0 : (bi > DIM - 2 ? DIM - 2 : bi);
    rd = tr - (float)ri;
    gd = tg - (float)gi;
    bd = tb - (float)bi;
    base = bi * DIM2 + gi * DIM + ri;
}

// ---------------------------------------------------------------------------
// C-stage (one pixel): weights + unpack + FMA tree.
// BYTE-IDENTICAL accumulate order to the verified 65us kernel.
// ---------------------------------------------------------------------------
__device__ __forceinline__ void c1(float rd, float gd, float bd,
                                   const v2u& A, const v2u& B, const v2u& C, const v2u& D,
                                   float& o0, float& o1, float& o2)
{
    const float dq = 1.0f / 1023.0f;
    unsigned c000 = A.x, c001 = A.y, c010 = B.x, c011 = B.y;
    unsigned c100 = C.x, c101 = C.y, c110 = D.x, c111 = D.y;

    float wr1 = rd, wr0 = 1.0f - rd;
    float wg1 = gd, wg0 = 1.0f - gd;
    float wb1 = bd, wb0 = 1.0f - bd;

    float w000 = wb0 * wg0 * wr0;
    float w001 = wb0 * wg0 * wr1;
    float w010 = wb0 * wg1 * wr0;
    float w011 = wb0 * wg1 * wr1;
    float w100 = wb1 * wg0 * wr0;
    float w101 = wb1 * wg0 * wr1;
    float w110 = wb1 * wg1 * wr0;
    float w111 = wb1 * wg1 * wr1;

    float a0 = w000 * (float)(c000 & 1023u) + w001 * (float)(c001 & 1023u)
             + w010 * (float)(c010 & 1023u) + w011 * (float)(c011 & 1023u)
             + w100 * (float)(c100 & 1023u) + w101 * (float)(c101 & 1023u)
             + w110 * (float)(c110 & 1023u) + w111 * (float)(c111 & 1023u);

    float a1 = w000 * (float)((c000 >> 10) & 1023u) + w001 * (float)((c001 >> 10) & 1023u)
             + w010 * (float)((c010 >> 10) & 1023u) + w011 * (float)((c011 >> 10) & 1023u)
             + w100 * (float)((c100 >> 10) & 1023u) + w101 * (float)((c101 >> 10) & 1023u)
             + w110 * (float)((c110 >> 10) & 1023u) + w111 * (float)((c111 >> 10) & 1023u);

    float a2 = w000 * (float)(c000 >> 20) + w001 * (float)(c001 >> 20)
             + w010 * (float)(c010 >> 20) + w011 * (float)(c011 >> 20)
             + w100 * (float)(c100 >> 20) + w101 * (float)(c101 >> 20)
             + w110 * (float)(c110 >> 20) + w111 * (float)(c111 >> 20);

    o0 = a0 * dq;
    o1 = a1 * dq;
    o2 = a2 * dq;
}

// ---------------------------------------------------------------------------
// Main kernel: 4-deep LDS-gather pipeline as literal ISA. Per image:
//   issue 16 ds_read2 (asm, px0..px3) | global prefetch |
//   lgkmcnt(12)->consume px0 | (8)->px1 | (4)->px2 | (0)->px3 | store.
// In-loop LGKM ops are exactly these 16 DS instructions, so the counted
// waits are exact; DS returns are in-order within the LDS pipe.
// ---------------------------------------------------------------------------
template <bool PREPACKED>
__global__ __launch_bounds__(1024) void lut3d_apply_kernel(
    const unsigned int* __restrict__ plut,   // packed LUT in workspace (PREPACKED)
    const float* __restrict__ lut,           // raw LUT (fallback path)
    const float* __restrict__ x,             // (8, 3, 1024, 1024)
    float* __restrict__ out)                 // (8, 3, 1024, 1024)
{
    extern __shared__ unsigned int sLut[];   // DIM3 dwords, LDS offset 0

    if constexpr (PREPACKED) {
        const uint4* p4 = reinterpret_cast<const uint4*>(plut);
        uint4* s4 = reinterpret_cast<uint4*>(sLut);
        for (int i = threadIdx.x; i < DIM3 / 4; i += 1024) s4[i] = p4[i];
        if (threadIdx.x == 0) sLut[DIM3 - 1] = plut[DIM3 - 1];
    } else {
        for (int i = threadIdx.x; i < DIM3; i += 1024) {
            float v0 = lut[i];
            float v1 = lut[DIM3 + i];
            float v2 = lut[2 * DIM3 + i];
            unsigned q0 = (unsigned)(fminf(fmaxf(v0, 0.0f), 1.0f) * 1023.0f + 0.5f);
            unsigned q1 = (unsigned)(fminf(fmaxf(v1, 0.0f), 1.0f) * 1023.0f + 0.5f);
            unsigned q2 = (unsigned)(fminf(fmaxf(v2, 0.0f), 1.0f) * 1023.0f + 0.5f);
            sLut[i] = q0 | (q1 << 10) | (q2 << 20);
        }
    }
    __syncthreads();

    // 32-bit LDS byte address of the LUT (generic shared ptr: low 32 bits
    // carry the LDS offset; with no static __shared__ this is 0).
    const unsigned lutByteBase = (unsigned)(unsigned long long)(const void*)sLut;

    const int q = blockIdx.x * blockDim.x + threadIdx.x;   // [0, GROUPS_PER_IMG)
    const float4* __restrict__ xp = reinterpret_cast<const float4*>(x);
    float4* __restrict__ op = reinterpret_cast<float4*>(out);

    auto iplane = [&](int img, int ch) -> size_t {
        return ((size_t)img * 3 + ch) * GROUPS_PER_IMG + q;
    };

    float4 rv = xp[iplane(0, 0)], gv = xp[iplane(0, 1)], bv = xp[iplane(0, 2)];

#pragma unroll 1
    for (int b = 0; b < BATCH; ++b) {
        float rd0, gd0, bd0, rd1, gd1, bd1, rd2, gd2, bd2, rd3, gd3, bd3;
        int b0, b1, b2, b3;
        idx_px(rv.x, gv.x, bv.x, rd0, gd0, bd0, b0);
        idx_px(rv.y, gv.y, bv.y, rd1, gd1, bd1, b1);
        idx_px(rv.z, gv.z, bv.z, rd2, gd2, bd2, b2);
        idx_px(rv.w, gv.w, bv.w, rd3, gd3, bd3, b3);

        // ---- issue all 16 ds_read2_b32 (volatile asm: order guaranteed) ----
        v2u A0, B0, C0, D0, A1, B1, C1, D1, A2, B2, C2, D2, A3, B3, C3, D3;
        gather_px(lutByteBase, b0, A0, B0, C0, D0);
        gather_px(lutByteBase, b1, A1, B1, C1, D1);
        gather_px(lutByteBase, b2, A2, B2, C2, D2);
        gather_px(lutByteBase, b3, A3, B3, C3, D3);

        // global prefetch of next image rides under the LDS pipeline (vmcnt)
        int nx = b + 1 < BATCH ? b + 1 : b;
        float4 rn = xp[iplane(nx, 0)];
        float4 gn = xp[iplane(nx, 1)];
        float4 bn = xp[iplane(nx, 2)];

        // ---- consume in issue order with exact counted waits ----
        float o00, o01, o02, o10, o11, o12, o20, o21, o22, o30, o31, o32;
        WAITPIN(12, A0, B0, C0, D0);
        c1(rd0, gd0, bd0, A0, B0, C0, D0, o00, o01, o02);
        WAITPIN(8, A1, B1, C1, D1);
        c1(rd1, gd1, bd1, A1, B1, C1, D1, o10, o11, o12);
        WAITPIN(4, A2, B2, C2, D2);
        c1(rd2, gd2, bd2, A2, B2, C2, D2, o20, o21, o22);
        WAITPIN(0, A3, B3, C3, D3);
        c1(rd3, gd3, bd3, A3, B3, C3, D3, o30, o31, o32);

        op[iplane(b, 0)] = make_float4(o00, o10, o20, o30);
        op[iplane(b, 1)] = make_float4(o01, o11, o21, o31);
        op[iplane(b, 2)] = make_float4(o02, o12, o22, o32);

        rv = rn; gv = gn; bv = bn;
    }
}

extern "C" void kernel_launch(void* const* d_in, const int* in_sizes, int n_in,
                              void* d_out, int out_size, void* d_ws, size_t ws_size,
                              hipStream_t stream) {
    const float* lut = (const float*)d_in[0];  // 3*33*33*33
    const float* x   = (const float*)d_in[1];  // 8*3*1024*1024
    float* out = (float*)d_out;

    // 140 KB LDS -> 1 block/CU; 1024 threads = 16 waves/CU; 256 blocks = 1/CU.
    if (ws_size >= (size_t)LDS_BYTES && d_ws != nullptr) {
        unsigned int* packed = (unsigned int*)d_ws;
        lut_pack_kernel<<<(DIM3 + 255) / 256, 256, 0, stream>>>(lut, packed);
        lut3d_apply_kernel<true><<<256, 1024, LDS_BYTES, stream>>>(packed, lut, x, out);
    } else {
        lut3d_apply_kernel<false><<<256, 1024, LDS_BYTES, stream>>>(nullptr, lut, x, out);
    }
}